// Round 8
// baseline (419.874 us; speedup 1.0000x reference)
//
#include <hip/hip_runtime.h>
#include <cstdint>
#include <cstddef>

// DynamicHierarchicalAttention — MFMA pipeline.
// R19: attn2 rebuilt barrier-free.  Evidence: attn2 stuck at 58-65us across
// k128/k64, 224/132 VGPR, 1024/2048 blocks (R16/R18) — duration == 54.6MB
// traffic at 930 GB/s, i.e. latency-bound with ~10 loads in flight (8 serial
// per-head barrier rounds).  R17's spill accident showed the same kernel can
// stream 3.5 TB/s when enough requests are outstanding.  Fix: drop K-LDS
// staging entirely (the staging was identity-indexed; B-fragments gather
// directly from qkv — 16 full 64B lines per instruction), keep only Linv in
// LDS (one barrier), waves free-run with K prefetched one step and Q two
// heads ahead.  #pragma unroll 1 on the h-loop blocks the full-unroll VGPR
// blowup seen in R16.  Bit-identical arithmetic and accumulation order.
// Everything else identical to R18.

#define TB 2
#define TT 2048
#define TD 512
#define TH 8
#define THD 64
#define KC 4   // k-chunks in attn1

#define MI_M1 0
#define MI_M2 1
#define MI_NTOK 2
#define MI_OFF_CW 3
#define MI_OFF_BW 4
#define MI_OFF_GW 5
#define MI_MCHAR 6
#define MI_MBLOCK 7
#define MI_MGLOB 8
#define MI_SEQC 9
#define MI_SEQB 10
#define MI_SEQG 11

typedef _Float16 half8 __attribute__((ext_vector_type(8)));
typedef _Float16 half4 __attribute__((ext_vector_type(4)));
typedef _Float16 half2_t __attribute__((ext_vector_type(2)));
typedef float floatx4 __attribute__((ext_vector_type(4)));

__device__ __forceinline__ floatx4 mfma16(half8 a, half8 b, floatx4 c) {
  return __builtin_amdgcn_mfma_f32_16x16x32_f16(a, b, c, 0, 0, 0);
}
__device__ __forceinline__ floatx4 mfma16k16(half4 a, half4 b, floatx4 c) {
  return __builtin_amdgcn_mfma_f32_16x16x16f16(a, b, c, 0, 0, 0);
}

// barrier that does NOT drain vmcnt: LDS writes visible, global prefetch
// loads stay in flight across the barrier.
__device__ __forceinline__ void barrier_nodrain() {
  asm volatile("s_waitcnt lgkmcnt(0)" ::: "memory");
  __builtin_amdgcn_s_barrier();
}

__device__ __forceinline__ double fracd(double x) { return x - floor(x); }

// ---------------------------------------------------------------------------
// parallel boundary scan for one phase: n elements, increment c.
// ---------------------------------------------------------------------------
__device__ int scan_phase(int n, double c, int* __restrict__ ids,
                          int* __restrict__ startg, float* __restrict__ cntg,
                          int* __restrict__ wsum, int t)
{
  int loc[8];
  const int base = t * 8;
#pragma unroll
  for (int j = 0; j < 8; ++j) {
    const int i = base + j;
    int f = 0;
    if (i < n) {
      const int pidx = (i == 0) ? n : i;   // roll: prev of elem 0 is elem n-1
      f = (fracd((double)(i + 1) * c) < fracd((double)pidx * c)) ? 1 : 0;
    }
    loc[j] = f + ((j > 0) ? loc[j - 1] : 0);
  }
  wsum[t] = loc[7];
  __syncthreads();
  for (int off = 1; off < 256; off <<= 1) {
    int u = 0;
    if (t >= off) u = wsum[t - off];
    __syncthreads();
    wsum[t] += u;
    __syncthreads();
  }
  const int excl = wsum[t] - loc[7];
  const int m = wsum[255];
#pragma unroll
  for (int j = 0; j < 8; ++j) {
    const int i = base + j;
    if (i < n) {
      const int id = excl + loc[j];
      ids[i] = id;
      const int f = loc[j] - ((j > 0) ? loc[j - 1] : 0);
      if (f) startg[id - 1] = i;
    }
  }
  __syncthreads();
  for (int j = t; j < m; j += 256)
    cntg[j] = (float)((((j + 1) < m) ? startg[j + 1] : n) - startg[j]);
  __syncthreads();
  return m;
}

// ---------------------------------------------------------------------------
// Fused meta (blockIdx.y==7, x==0: 1-block scan) + prep conversions
// (blockIdx.y<7: x->f16, Wi->f16, Wo->hi/lo f16 split).
// ---------------------------------------------------------------------------
__global__ __launch_bounds__(256)
void meta_prep(const float* __restrict__ mw, const float* __restrict__ mb,
               const float* __restrict__ gw, const float* __restrict__ gb,
               int* __restrict__ mi,
               int* __restrict__ start1, float* __restrict__ cnt1,
               int* __restrict__ start2, float* __restrict__ cnt2,
               int* __restrict__ gmap,
               const float* __restrict__ x,
               const float* __restrict__ wi0, const float* __restrict__ wi1,
               const float* __restrict__ wi2,
               const float* __restrict__ wo0, const float* __restrict__ wo1,
               const float* __restrict__ wo2,
               _Float16* __restrict__ xh, _Float16* __restrict__ wiH,
               _Float16* __restrict__ woH, _Float16* __restrict__ woL)
{
  __shared__ int ids1[TT];
  __shared__ int ids2[TT];
  __shared__ int wsum[256];
  __shared__ double dsh[256];
  const int t = threadIdx.x;

  if (blockIdx.y == 7) {
    if (blockIdx.x != 0) return;
    double s1 = 0.0, s2 = 0.0;
    for (int i = t; i < TD; i += 256) { s1 += (double)mw[i]; s2 += (double)gw[i]; }
    dsh[t] = s1; __syncthreads();
    for (int off = 128; off > 0; off >>= 1) {
      if (t < off) dsh[t] += dsh[t + off];
      __syncthreads();
    }
    const double c1 = dsh[0] + (double)mb[0];
    __syncthreads();
    dsh[t] = s2; __syncthreads();
    for (int off = 128; off > 0; off >>= 1) {
      if (t < off) dsh[t] += dsh[t + off];
      __syncthreads();
    }
    const double c2 = dsh[0] + (double)gb[0];
    __syncthreads();

    const int m1 = scan_phase(TT, c1, ids1, start1, cnt1, wsum, t);
    const int m2 = scan_phase(m1, c2, ids2, start2, cnt2, wsum, t);

    int i0 = TT;
    if (m1 >= 1 && m2 >= 1) i0 = start1[start2[0]];
    const int ntok = TT - i0;

    if (t == 0) {
      mi[MI_M1] = m1; mi[MI_M2] = m2; mi[MI_NTOK] = ntok;
      const int offcw = TB * ntok * TD;
      mi[MI_OFF_CW] = offcw;
      mi[MI_OFF_BW] = offcw + TB * TT * TT;
      mi[MI_OFF_GW] = offcw + TB * TT * TT + TB * m1 * m1;
      mi[MI_MCHAR] = TB * TT;
      mi[MI_MBLOCK] = TB * m1;
      mi[MI_MGLOB] = TB * m2;
      mi[MI_SEQC] = TT;
      mi[MI_SEQB] = m1;
      mi[MI_SEQG] = m2;
    }
    for (int i = i0 + t; i < TT; i += 256)
      gmap[i - i0] = ids2[ids1[i] - 1] - 1;
    return;
  }

  // --- prep regions ---
  const int r = blockIdx.y;
  const float* src;
  _Float16* dh;
  _Float16* dl = nullptr;
  int n;
  if (r == 0)      { src = x;   dh = xh;                              n = TB * TT * TD; }
  else if (r == 1) { src = wi0; dh = wiH;                             n = 3 * TD * TD; }
  else if (r == 2) { src = wi1; dh = wiH + (size_t)1 * 3 * TD * TD;   n = 3 * TD * TD; }
  else if (r == 3) { src = wi2; dh = wiH + (size_t)2 * 3 * TD * TD;   n = 3 * TD * TD; }
  else if (r == 4) { src = wo0; dh = woH; dl = woL;                   n = TD * TD; }
  else if (r == 5) { src = wo1; dh = woH + (size_t)TD * TD; dl = woL + (size_t)TD * TD; n = TD * TD; }
  else             { src = wo2; dh = woH + (size_t)2 * TD * TD; dl = woL + (size_t)2 * TD * TD; n = TD * TD; }

  const int stride = gridDim.x * 256 * 4;
  for (int i = (blockIdx.x * 256 + threadIdx.x) * 4; i < n; i += stride) {
    const float4 v = *(const float4*)&src[i];
    const float a[4] = {v.x, v.y, v.z, v.w};
    half4 h, l;
#pragma unroll
    for (int e = 0; e < 4; ++e) {
      const _Float16 hh = (_Float16)a[e];
      h[e] = hh;
      l[e] = (_Float16)(a[e] - (float)hh);
    }
    *(half4*)&dh[i] = h;
    if (dl) *(half4*)&dl[i] = l;
  }
}

// ---------------------------------------------------------------------------
// qkv GEMM 128m x 64n tile, pure-f16 staging, 2-phase pipelined.
// C[M,N] = A[M,512] @ W[N,512]^T + bias.  Q columns (bn<512) scaled by 0.125.
// ---------------------------------------------------------------------------
__global__ __launch_bounds__(256)
void gemm_mfma(const _Float16* __restrict__ A, const _Float16* __restrict__ W,
               const float* __restrict__ bias, _Float16* __restrict__ C,
               const int* __restrict__ mi, int m_slot, int N)
{
  const int M = mi[m_slot];
  const int bm = blockIdx.y * 128;
  if (bm >= M) return;
  const int bn = blockIdx.x * 64;
  __shared__ _Float16 Ah[2][128][40];
  __shared__ _Float16 Wh[2][64][40];

  const int t = threadIdx.x;
  const int wv = t >> 6;
  const int lane = t & 63;
  const int l15 = lane & 15;
  const int quad = lane >> 4;
  const int srowA = t >> 1;
  const int ssegA = (t & 1) * 16;
  const int srowW = t >> 2;
  const int ssegW = (t & 3) * 8;
  const int ar = bm + srowA;
  const size_t abase = (size_t)ar * TD + ssegA;
  const size_t wbase = (size_t)(bn + srowW) * TD + ssegW;

  floatx4 acc[2][4];
#pragma unroll
  for (int i = 0; i < 2; ++i)
#pragma unroll
    for (int j = 0; j < 4; ++j) acc[i][j] = (floatx4){0.f, 0.f, 0.f, 0.f};

  const half8 h8z = {};
  half8 pa0, pa1, pw;

  auto LOADT = [&](int kk) {
    pa0 = h8z; pa1 = h8z;
    if (ar < M) {
      pa0 = *(const half8*)&A[abase + kk];
      pa1 = *(const half8*)&A[abase + kk + 8];
    }
    pw = *(const half8*)&W[wbase + kk];
  };
  auto WRITET = [&](int buf) {
    *(half8*)&Ah[buf][srowA][ssegA] = pa0;
    *(half8*)&Ah[buf][srowA][ssegA + 8] = pa1;
    *(half8*)&Wh[buf][srowW][ssegW] = pw;
  };

  LOADT(0);
  for (int it = 0; it < TD / 32; ++it) {
    const int buf = it & 1;
    WRITET(buf);
    if (it + 1 < TD / 32) LOADT((it + 1) * 32);
    barrier_nodrain();
    half8 ah[2];
#pragma unroll
    for (int mp = 0; mp < 2; ++mp)
      ah[mp] = *(const half8*)&Ah[buf][wv * 32 + mp * 16 + l15][quad * 8];
#pragma unroll
    for (int np = 0; np < 4; ++np) {
      const half8 bh = *(const half8*)&Wh[buf][np * 16 + l15][quad * 8];
#pragma unroll
      for (int mp = 0; mp < 2; ++mp)
        acc[mp][np] = mfma16(ah[mp], bh, acc[mp][np]);
    }
  }
  const float qs = (bn < 512) ? 0.125f : 1.0f;   // fold softmax temperature into Q
  float bv[4];
#pragma unroll
  for (int np = 0; np < 4; ++np) bv[np] = bias[bn + np * 16 + l15];
#pragma unroll
  for (int mp = 0; mp < 2; ++mp) {
#pragma unroll
    for (int r = 0; r < 4; ++r) {
      const int row = bm + wv * 32 + mp * 16 + quad * 4 + r;
      if (row < M) {
        _Float16* cp = &C[(size_t)row * N + bn];
#pragma unroll
        for (int np = 0; np < 4; ++np)
          cp[np * 16 + l15] = (_Float16)((acc[mp][np][r] + bv[np]) * qs);
      }
    }
  }
}

// ---------------------------------------------------------------------------
// Proj GEMM with fused combine, 64m x 64n tile, split-f16 (pre-split W),
// 2-phase pipelined.
// ---------------------------------------------------------------------------
__global__ __launch_bounds__(256)
void gemm_norm_mfma(const _Float16* __restrict__ Ob, const float* __restrict__ lb,
                    const _Float16* __restrict__ Whg, const _Float16* __restrict__ Wlg,
                    const float* __restrict__ bias,
                    float* __restrict__ C, const int* __restrict__ mi,
                    int m_slot, int seq_slot)
{
  const int M = mi[m_slot];
  const int bm = blockIdx.y * 64;
  if (bm >= M) return;
  const int seq = mi[seq_slot];
  const int bn = blockIdx.x * 64;
  __shared__ _Float16 Ah[2][64][40];
  __shared__ _Float16 Al[2][64][40];
  __shared__ _Float16 Wh[2][64][40];
  __shared__ _Float16 Wl[2][64][40];

  const int t = threadIdx.x;
  const int wv = t >> 6;
  const int lane = t & 63;
  const int l15 = lane & 15;
  const int quad = lane >> 4;
  const int srow = t >> 2;
  const int sseg = (t & 3) * 8;

  const int ar = bm + srow;
  const int ab = (ar >= seq) ? 1 : 0;
  const int aq = ar - ab * seq;
  const size_t wbase = (size_t)(bn + srow) * TD + sseg;

  floatx4 acc[4];
#pragma unroll
  for (int j = 0; j < 4; ++j) acc[j] = (floatx4){0.f, 0.f, 0.f, 0.f};

  const half8 h8z = {};
  half8 pOb[KC];
  float plb[KC];
  half8 pwh, pwl;

  auto LOADT = [&](int kk) {
    if (ar < M) {
      const size_t off = (size_t)ar * TD + kk + sseg;
#pragma unroll
      for (int z = 0; z < KC; ++z)
        pOb[z] = *(const half8*)&Ob[(size_t)z * 2097152 + off];
      const int h = kk >> 6;
      const size_t lidx = ((size_t)(ab * TH + h)) * 2048 + aq;
#pragma unroll
      for (int z = 0; z < KC; ++z) plb[z] = lb[(size_t)z * 32768 + lidx];
    } else {
#pragma unroll
      for (int z = 0; z < KC; ++z) { pOb[z] = h8z; plb[z] = 1.f; }
    }
    pwh = *(const half8*)&Whg[wbase + kk];
    pwl = *(const half8*)&Wlg[wbase + kk];
  };
  auto WRITET = [&](int buf) {
    float aa[8] = {0.f, 0.f, 0.f, 0.f, 0.f, 0.f, 0.f, 0.f};
    if (ar < M) {
#pragma unroll
      for (int z = 0; z < KC; ++z)
#pragma unroll
        for (int e = 0; e < 8; ++e) aa[e] += (float)pOb[z][e];
      const float lt = plb[0] + plb[1] + plb[2] + plb[3];
      const float linv = 1.f / lt;
#pragma unroll
      for (int e = 0; e < 8; ++e) aa[e] *= linv;
    }
    half8 hi, lo;
#pragma unroll
    for (int e = 0; e < 8; ++e) {
      const _Float16 h = (_Float16)aa[e];
      hi[e] = h; lo[e] = (_Float16)(aa[e] - (float)h);
    }
    *(half8*)&Ah[buf][srow][sseg] = hi;
    *(half8*)&Al[buf][srow][sseg] = lo;
    *(half8*)&Wh[buf][srow][sseg] = pwh;
    *(half8*)&Wl[buf][srow][sseg] = pwl;
  };

  LOADT(0);
  for (int it = 0; it < TD / 32; ++it) {
    const int buf = it & 1;
    WRITET(buf);
    if (it + 1 < TD / 32) LOADT((it + 1) * 32);
    barrier_nodrain();
    const half8 ah = *(const half8*)&Ah[buf][wv * 16 + l15][quad * 8];
    const half8 al = *(const half8*)&Al[buf][wv * 16 + l15][quad * 8];
#pragma unroll
    for (int np = 0; np < 4; ++np) {
      const half8 bh = *(const half8*)&Wh[buf][np * 16 + l15][quad * 8];
      const half8 bl = *(const half8*)&Wl[buf][np * 16 + l15][quad * 8];
      acc[np] = mfma16(al, bh, acc[np]);
      acc[np] = mfma16(ah, bl, acc[np]);
      acc[np] = mfma16(ah, bh, acc[np]);
    }
  }
  float bv[4];
#pragma unroll
  for (int np = 0; np < 4; ++np) bv[np] = bias[bn + np * 16 + l15];
#pragma unroll
  for (int r = 0; r < 4; ++r) {
    const int row = bm + wv * 16 + quad * 4 + r;
    if (row < M) {
      float* cp = &C[(size_t)row * 512 + bn];
#pragma unroll
      for (int np = 0; np < 4; ++np)
        cp[np * 16 + l15] = acc[np][r] + bv[np];
    }
  }
}

// ---------------------------------------------------------------------------
// attn pass1, split-K x4 (z = chunk), S^T-trick, 2-phase pipelined K/V LDS.
// q-tile 128, 4 waves x 32 q (natural ~80 VGPR, 4 blocks/CU).
// Q pre-scaled by 0.125.
// ---------------------------------------------------------------------------
__global__ __launch_bounds__(256)
void attn1_mfma(const _Float16* __restrict__ qkv,
                float* __restrict__ lbase, _Float16* __restrict__ Obase,
                const int* __restrict__ mi, int seq_slot)
{
  const int seq = mi[seq_slot];
  const int q0 = blockIdx.x * 128;
  if (q0 >= seq) return;
  const int b = blockIdx.y >> 3, h = blockIdx.y & 7;
  const int z = blockIdx.z;
  float* lP = lbase + (size_t)z * 32768;
  _Float16* oP = Obase + (size_t)z * 2097152;
  const int t = threadIdx.x;
  const int wv = t >> 6;
  const int lane = t & 63;
  const int l15 = lane & 15;
  const int quad = lane >> 4;

  __shared__ __align__(16) char smem_raw[36864];   // 2 x (Kf 9216 + Vt 9216)
  float (*Ot)[68] = (float (*)[68])smem_raw;       // epilogue reuse (buf 0)

  half8 qB[2][2];
#pragma unroll
  for (int mp = 0; mp < 2; ++mp) {
    const int qrow = q0 + wv * 32 + mp * 16 + l15;
#pragma unroll
    for (int c = 0; c < 2; ++c) {
      half8 v = {};
      if (qrow < seq)
        v = *(const half8*)&qkv[((size_t)(b * seq + qrow)) * 1536 + h * 64 + c * 32 + quad * 8];
      qB[mp][c] = v;
    }
  }
  half4 onesA;
#pragma unroll
  for (int j = 0; j < 4; ++j) onesA[j] = (_Float16)1.0f;

  floatx4 oacc[2][4];
#pragma unroll
  for (int i = 0; i < 2; ++i)
#pragma unroll
    for (int j = 0; j < 4; ++j) oacc[i][j] = (floatx4){0.f, 0.f, 0.f, 0.f};
  floatx4 lacc[2] = {(floatx4){0.f, 0.f, 0.f, 0.f}, (floatx4){0.f, 0.f, 0.f, 0.f}};

  const int nkt = (seq + 63) >> 6;
  const int nkc = (nkt + KC - 1) / KC;
  const int kt_beg = z * nkc;
  const int kt_end = min(kt_beg + nkc, nkt);

  // staging geometry
  const int krow = t >> 2;
  const int kseg = (t & 3) * 16;
  const int tp = lane & 31;
  const int dsel = lane >> 5;
  const int dbase = wv * 16 + dsel * 8;

  const half8 h8z = {};
  half8 pk0, pk1, pva, pvb;

  auto LOADKV = [&](int kt) {
    const int k0 = kt * 64;
    pk0 = h8z; pk1 = h8z; pva = h8z; pvb = h8z;
    const int kg = k0 + krow;
    if (kg < seq) {
      const _Float16* base = &qkv[((size_t)(b * seq + kg)) * 1536 + 512 + h * 64 + kseg];
      pk0 = *(const half8*)base;
      pk1 = *(const half8*)(base + 8);
    }
    const int kg0 = k0 + tp * 2;
    if (kg0 < seq)
      pva = *(const half8*)&qkv[((size_t)(b * seq + kg0)) * 1536 + 1024 + h * 64 + dbase];
    if (kg0 + 1 < seq)
      pvb = *(const half8*)&qkv[((size_t)(b * seq + kg0 + 1)) * 1536 + 1024 + h * 64 + dbase];
  };

  LOADKV(kt_beg);
  for (int kt = kt_beg; kt < kt_end; ++kt) {
    char* sb = smem_raw + (size_t)((kt - kt_beg) & 1) * 18432;
    _Float16 (*Kf)[72] = (_Float16 (*)[72])sb;
    _Float16 (*Vt)[72] = (_Float16 (*)[72])(sb + 9216);

    *(half8*)&Kf[krow][kseg] = pk0;
    *(half8*)&Kf[krow][kseg + 8] = pk1;
#pragma unroll
    for (int j = 0; j < 8; ++j) {
      half2_t pkk; pkk[0] = pva[j]; pkk[1] = pvb[j];
      *(half2_t*)&Vt[dbase + j][tp * 2] = pkk;
    }
    if (kt + 1 < kt_end) LOADKV(kt + 1);
    barrier_nodrain();

    const int k0 = kt * 64;
    const bool kfull = (k0 + 64 <= seq);
#pragma unroll
    for (int p = 0; p < 4; ++p) {
      floatx4 sT[2] = {(floatx4){0.f, 0.f, 0.f, 0.f}, (floatx4){0.f, 0.f, 0.f, 0.f}};
#pragma unroll
      for (int c = 0; c < 2; ++c) {
        const half8 kA = *(const half8*)&Kf[p * 16 + l15][c * 32 + quad * 8];
#pragma unroll
        for (int mp = 0; mp < 2; ++mp)
          sT[mp] = mfma16(kA, qB[mp][c], sT[mp]);
      }
      half4 vA[4];
#pragma unroll
      for (int dblk = 0; dblk < 4; ++dblk)
        vA[dblk] = *(const half4*)&Vt[dblk * 16 + l15][p * 16 + quad * 4];
      const int kg = k0 + p * 16 + quad * 4;
#pragma unroll
      for (int mp = 0; mp < 2; ++mp) {
        half4 eB;
        if (kfull) {
#pragma unroll
          for (int r = 0; r < 4; ++r)
            eB[r] = (_Float16)__expf(sT[mp][r]);
        } else {
#pragma unroll
          for (int r = 0; r < 4; ++r) {
            const float e = (kg + r < seq) ? __expf(sT[mp][r]) : 0.f;
            eB[r] = (_Float16)e;
          }
        }
        lacc[mp] = mfma16k16(onesA, eB, lacc[mp]);
#pragma unroll
        for (int dblk = 0; dblk < 4; ++dblk)
          oacc[mp][dblk] = mfma16k16(vA[dblk], eB, oacc[mp][dblk]);
      }
    }
  }

  __syncthreads();   // K/V LDS done — reuse as Ot

#pragma unroll
  for (int mp = 0; mp < 2; ++mp) {
#pragma unroll
    for (int dblk = 0; dblk < 4; ++dblk)
      *(floatx4*)&Ot[wv * 16 + l15][dblk * 16 + quad * 4] = oacc[mp][dblk];
    const int ql = lane >> 2;
    const int dseg = (lane & 3) * 4;
    const int qg = q0 + wv * 32 + mp * 16 + ql;
    if (qg < seq) {
      _Float16* op = &oP[((size_t)(b * seq + qg)) * 512 + h * 64];
#pragma unroll
      for (int u = 0; u < 4; ++u) {
        const float4 v = *(const float4*)&Ot[wv * 16 + ql][u * 16 + dseg];
        half4 hv;
        hv[0] = (_Float16)v.x; hv[1] = (_Float16)v.y;
        hv[2] = (_Float16)v.z; hv[3] = (_Float16)v.w;
        *(half4*)(op + u * 16 + dseg) = hv;
      }
    }
    if (quad == 0) {
      const int qg2 = q0 + wv * 32 + mp * 16 + l15;
      if (qg2 < seq)
        lP[((size_t)(b * TH + h)) * 2048 + qg2] = lacc[mp][0];
    }
  }
}

// ---------------------------------------------------------------------------
// attn pass2, R19: barrier-free.  No K LDS staging — B-fragments gather
// directly from qkv (identical bytes the old staging copied).  One barrier
// total (Linv).  K prefetched one (h,np)-step ahead, Q two heads ahead.
// q-tile 64 x k-tile 64; Q pre-scaled by 0.125; final *0.125 = head mean.
// ---------------------------------------------------------------------------
__global__ __launch_bounds__(256)
void attn2_mfma(const _Float16* __restrict__ qkv,
                const float* __restrict__ lb,
                float* __restrict__ outb, const int* __restrict__ mi,
                int seq_slot, int off_slot)
{
  const int seq = mi[seq_slot];
  const int q0 = blockIdx.y * 64;
  const int k0 = blockIdx.x * 64;
  if (q0 >= seq || k0 >= seq) return;
  const int b = blockIdx.z;
  const int woff = mi[off_slot];
  float* wout = outb + (size_t)woff + (size_t)b * seq * seq;

  __shared__ float Linv8[TH][64];

  const int t = threadIdx.x;
  const int wv = t >> 6;
  const int lane = t & 63;
  const int l15 = lane & 15;
  const int quad = lane >> 4;

  // all-heads Linv, once (the kernel's only barrier)
  for (int i = t; i < TH * 64; i += 256) {
    const int hh = i >> 6;
    const int qq = i & 63;
    float lv = 1.f;
    if (q0 + qq < seq) {
      const size_t lidx = ((size_t)(b * TH + hh)) * 2048 + q0 + qq;
      float lt = 0.f;
#pragma unroll
      for (int zz = 0; zz < KC; ++zz) lt += lb[(size_t)zz * 32768 + lidx];
      lv = lt;
    }
    Linv8[hh][qq] = 1.f / lv;
  }
  __syncthreads();

  floatx4 acc[4];
#pragma unroll
  for (int j = 0; j < 4; ++j) acc[j] = (floatx4){0.f, 0.f, 0.f, 0.f};

  const int qr = q0 + wv * 16 + l15;
  const bool qok = (qr < seq);
  const size_t qoff = (size_t)(b * seq + qr) * 1536 + quad * 8;
  // K gather: row k0 + np*16 + l15, col h*64 + quad*8 (and +32)
  const int krbase = k0 + l15;
  const size_t kbase = ((size_t)(b * seq + krbase)) * 1536 + 512 + quad * 8;

  const half8 h8z = {};
  half8 kc0, kc1;           // current K fragment pair (in flight)
  half8 qc0, qc1, qn0, qn1; // current / next-head Q

  auto LOADK = [&](int h, int np, half8& d0, half8& d1) {
    d0 = h8z; d1 = h8z;
    const int kr = krbase + np * 16;
    if (kr < seq) {
      const _Float16* p = &qkv[kbase + (size_t)np * 16 * 1536 + h * 64];
      d0 = *(const half8*)p;
      d1 = *(const half8*)(p + 32);
    }
  };
  auto LOADQ = [&](int h, half8& d0, half8& d1) {
    d0 = h8z; d1 = h8z;
    if (qok) {
      d0 = *(const half8*)&qkv[qoff + h * 64];
      d1 = *(const half8*)&qkv[qoff + h * 64 + 32];
    }
  };

  LOADK(0, 0, kc0, kc1);
  LOADQ(0, qc0, qc1);
  LOADQ(1, qn0, qn1);

#pragma unroll 1
  for (int h = 0; h < TH; ++h) {
    float lv[4];
#pragma unroll
    for (int r = 0; r < 4; ++r)
      lv[r] = Linv8[h][wv * 16 + quad * 4 + r];

#pragma unroll
    for (int np = 0; np < 4; ++np) {
      const half8 b0 = kc0, b1 = kc1;
      if (np < 3)           LOADK(h, np + 1, kc0, kc1);
      else if (h + 1 < TH)  LOADK(h + 1, 0, kc0, kc1);
      floatx4 s = (floatx4){0.f, 0.f, 0.f, 0.f};
      s = mfma16(qc0, b0, s);
      s = mfma16(qc1, b1, s);
#pragma unroll
      for (int r = 0; r < 4; ++r)
        acc[np][r] += __expf(s[r]) * lv[r];
    }
    if (h + 1 < TH) {
      qc0 = qn0; qc1 = qn1;
      if (h + 2 < TH) LOADQ(h + 2, qn0, qn1);
    }
  }

#pragma unroll
  for (int r = 0; r < 4; ++r) {
    const int qg = q0 + wv * 16 + quad * 4 + r;
    if (qg >= seq) continue;
    float* rowp = wout + (size_t)qg * seq;
#pragma unroll
    for (int np = 0; np < 4; ++np) {
      const int col = k0 + np * 16 + l15;
      if (col < seq) rowp[col] = acc[np][r] * 0.125f;
    }
  }
}

// ---------------------------------------------------------------------------
// merge: averages rows of src (f32) into f16 output (same rounding as before).
// ---------------------------------------------------------------------------
__global__ __launch_bounds__(256)
void merge_kernel(const float* __restrict__ src, _Float16* __restrict__ dst,
                  const int* __restrict__ start, const float* __restrict__ cnt,
                  const int* __restrict__ mi, int seqin_slot, int seqout_slot)
{
  const int j = blockIdx.x;
  const int b = blockIdx.y;
  const int seqo = mi[seqout_slot];
  if (j >= seqo) return;
  const int seqi = mi[seqin_slot];
  const int s = start[j];
  const float cf = cnt[j];
  const int n = (int)cf;
  const int d0 = threadIdx.x * 2;
  float s0 = 0.f, s1 = 0.f;
  const float* p = &src[((size_t)b * seqi + s) * TD + d0];
  for (int i = 0; i < n; ++i) {
    const float2 v = *(const float2*)p;
    s0 += v.x; s1 += v.y;
    p += TD;
  }
  const float inv = 1.f / (cf + 1e-10f);
  half2_t o;
  o[0] = (_Float16)(s0 * inv);
  o[1] = (_Float16)(s1 * inv);
  *(half2_t*)&dst[((size_t)b * seqo + j) * TD + d0] = o;
}

__global__ __launch_bounds__(256)
void expand_kernel(const float* __restrict__ gout, float* __restrict__ dout,
                   const int* __restrict__ gmap, const int* __restrict__ mi)
{
  const int j = blockIdx.x;
  const int b = blockIdx.y;
  const int ntok = mi[MI_NTOK];
  if (j >= ntok) return;
  const int m2 = mi[MI_M2];
  const int g = gmap[j];
  const int d0 = threadIdx.x * 2;
  const float2 v = *(const float2*)&gout[((size_t)b * m2 + g) * TD + d0];
  *(float2*)&dout[((size_t)b * ntok + j) * TD + d0] = v;
}

// ---------------------------------------------------------------------------
extern "C" void kernel_launch(void* const* d_in, const int* in_sizes, int n_in,
                              void* d_out, int out_size, void* d_ws, size_t ws_size,
                              hipStream_t stream)
{
  const float* x   = (const float*)d_in[0];
  const float* cWi = (const float*)d_in[1];
  const float* cbi = (const float*)d_in[2];
  const float* cWo = (const float*)d_in[3];
  const float* cbo = (const float*)d_in[4];
  const float* bWi = (const float*)d_in[5];
  const float* bbi = (const float*)d_in[6];
  const float* bWo = (const float*)d_in[7];
  const float* bbo = (const float*)d_in[8];
  const float* gWi = (const float*)d_in[9];
  const float* gbi = (const float*)d_in[10];
  const float* gWo = (const float*)d_in[11];
  const float* gbo = (const float*)d_in[12];
  const float* mw  = (const float*)d_in[13];
  const float* mbv = (const float*)d_in[14];
  const float* gw  = (const float*)d_in[15];
  const float* gbv = (const float*)d_in[16];
  float* outf = (float*)d_out;

  char* wsb = (char*)d_ws;
  int*   mi     = (int*)(wsb);
  int*   start1 = (int*)(wsb + 1024);
  float* cnt1   = (float*)(wsb + 1024 + 8192);
  int*   start2 = (int*)(wsb + 1024 + 2 * 8192);
  float* cnt2   = (float*)(wsb + 1024 + 3 * 8192);
  int*   gmap   = (int*)(wsb + 1024 + 4 * 8192);
  float* lbase  = (float*)(wsb + 65536);                    // KC x 32768 f32 (512 KB)
  _Float16* qkv = (_Float16*)(wsb + 655360);                // 4096x1536 f16 (12.6 MB)
  _Float16* Obase = (_Float16*)(wsb + 655360 + 12582912);   // KC x 4 MB f16
  float* stg_o  = (float*)(wsb + 30015488);                 // 8 MB f32
  _Float16* stg_mh = (_Float16*)(wsb + 38404096);           // 4 MB f16
  _Float16* xh  = (_Float16*)(wsb + 42598400);              // 4 MB f16
  _Float16* wiH = (_Float16*)(wsb + 46792704);              // 3 x 1536x512 f16 (4.7 MB)
  _Float16* woH = (_Float16*)(wsb + 51511296);              // 3 x 512x512 f16 (1.6 MB)
  _Float16* woL = (_Float16*)(wsb + 53084160);              // 3 x 512x512 f16 (1.6 MB)

  const dim3 blk(256);

  meta_prep<<<dim3(256, 8), blk, 0, stream>>>(mw, mbv, gw, gbv, mi, start1, cnt1,
                                              start2, cnt2, gmap,
                                              x, cWi, bWi, gWi, cWo, bWo, gWo,
                                              xh, wiH, woH, woL);

  // ---- char stage ----
  gemm_mfma<<<dim3(24, 32), blk, 0, stream>>>(xh, wiH, cbi, qkv, mi, MI_MCHAR, 1536);
  attn1_mfma<<<dim3(16, 16, KC), blk, 0, stream>>>(qkv, lbase, Obase, mi, MI_SEQC);
  attn2_mfma<<<dim3(32, 32, 2), blk, 0, stream>>>(qkv, lbase, outf, mi, MI_SEQC, MI_OFF_CW);
  gemm_norm_mfma<<<dim3(8, 64), blk, 0, stream>>>(Obase, lbase, woH, woL, cbo, stg_o, mi, MI_MCHAR, MI_SEQC);
  merge_kernel<<<dim3(2048, 2), blk, 0, stream>>>(stg_o, stg_mh, start1, cnt1, mi, MI_SEQC, MI_SEQB);

  // ---- block stage ----
  gemm_mfma<<<dim3(24, 32), blk, 0, stream>>>(stg_mh, wiH + (size_t)786432, bbi, qkv, mi, MI_MBLOCK, 1536);
  attn1_mfma<<<dim3(16, 16, KC), blk, 0, stream>>>(qkv, lbase, Obase, mi, MI_SEQB);
  attn2_mfma<<<dim3(32, 32, 2), blk, 0, stream>>>(qkv, lbase, outf, mi, MI_SEQB, MI_OFF_BW);
  gemm_norm_mfma<<<dim3(8, 64), blk, 0, stream>>>(Obase, lbase, woH + (size_t)262144, woL + (size_t)262144, bbo, stg_o, mi, MI_MBLOCK, MI_SEQB);
  merge_kernel<<<dim3(2048, 2), blk, 0, stream>>>(stg_o, stg_mh, start2, cnt2, mi, MI_SEQB, MI_SEQG);

  // ---- glob stage ----
  gemm_mfma<<<dim3(24, 32), blk, 0, stream>>>(stg_mh, wiH + (size_t)2 * 786432, gbi, qkv, mi, MI_MGLOB, 1536);
  attn1_mfma<<<dim3(16, 16, KC), blk, 0, stream>>>(qkv, lbase, Obase, mi, MI_SEQG);
  attn2_mfma<<<dim3(32, 32, 2), blk, 0, stream>>>(qkv, lbase, outf, mi, MI_SEQG, MI_OFF_GW);
  gemm_norm_mfma<<<dim3(8, 64), blk, 0, stream>>>(Obase, lbase, woH + (size_t)2 * 262144, woL + (size_t)2 * 262144, gbo, stg_o, mi, MI_MGLOB, MI_SEQG);
  expand_kernel<<<dim3(2048, 2), blk, 0, stream>>>(stg_o, outf, gmap, mi);

  (void)in_sizes; (void)n_in; (void)out_size; (void)ws_size;
}

// Round 9
// 328.356 us; speedup vs baseline: 1.2787x; 1.2787x over previous
//
#include <hip/hip_runtime.h>
#include <cstdint>
#include <cstddef>

// DynamicHierarchicalAttention — MFMA pipeline.
// R20: RESET to best-known (R13 = 332.8us) + meta_prep fusion only.
// Five rounds of attn2 variants (R14-R19) all regressed: R13's exact source
// ran <44us/stage, but every syntactic perturbation (drop one mul, re-tile,
// direct gather, launch_bounds) produced pathological codegen (224/132/64/48
// VGPR -> 58-149us).  Lesson: this kernel's codegen is chaotic in its
// source; restore byte-exact R13 kernels (gemm_mfma without Q-prescale,
// attn1/attn2 with __expf(s*0.125f), gemm_norm, f16 merge) and keep only
// the orthogonal meta+prep fusion (separate kernel, saves a launch).

#define TB 2
#define TT 2048
#define TD 512
#define TH 8
#define THD 64
#define KC 4   // k-chunks in attn1

#define MI_M1 0
#define MI_M2 1
#define MI_NTOK 2
#define MI_OFF_CW 3
#define MI_OFF_BW 4
#define MI_OFF_GW 5
#define MI_MCHAR 6
#define MI_MBLOCK 7
#define MI_MGLOB 8
#define MI_SEQC 9
#define MI_SEQB 10
#define MI_SEQG 11

typedef _Float16 half8 __attribute__((ext_vector_type(8)));
typedef _Float16 half4 __attribute__((ext_vector_type(4)));
typedef _Float16 half2_t __attribute__((ext_vector_type(2)));
typedef float floatx4 __attribute__((ext_vector_type(4)));

__device__ __forceinline__ floatx4 mfma16(half8 a, half8 b, floatx4 c) {
  return __builtin_amdgcn_mfma_f32_16x16x32_f16(a, b, c, 0, 0, 0);
}
__device__ __forceinline__ floatx4 mfma16k16(half4 a, half4 b, floatx4 c) {
  return __builtin_amdgcn_mfma_f32_16x16x16f16(a, b, c, 0, 0, 0);
}

// barrier that does NOT drain vmcnt: LDS writes visible, global prefetch
// loads stay in flight across the barrier.
__device__ __forceinline__ void barrier_nodrain() {
  asm volatile("s_waitcnt lgkmcnt(0)" ::: "memory");
  __builtin_amdgcn_s_barrier();
}

__device__ __forceinline__ double fracd(double x) { return x - floor(x); }

// ---------------------------------------------------------------------------
// parallel boundary scan for one phase: n elements, increment c.
// ---------------------------------------------------------------------------
__device__ int scan_phase(int n, double c, int* __restrict__ ids,
                          int* __restrict__ startg, float* __restrict__ cntg,
                          int* __restrict__ wsum, int t)
{
  int loc[8];
  const int base = t * 8;
#pragma unroll
  for (int j = 0; j < 8; ++j) {
    const int i = base + j;
    int f = 0;
    if (i < n) {
      const int pidx = (i == 0) ? n : i;   // roll: prev of elem 0 is elem n-1
      f = (fracd((double)(i + 1) * c) < fracd((double)pidx * c)) ? 1 : 0;
    }
    loc[j] = f + ((j > 0) ? loc[j - 1] : 0);
  }
  wsum[t] = loc[7];
  __syncthreads();
  for (int off = 1; off < 256; off <<= 1) {
    int u = 0;
    if (t >= off) u = wsum[t - off];
    __syncthreads();
    wsum[t] += u;
    __syncthreads();
  }
  const int excl = wsum[t] - loc[7];
  const int m = wsum[255];
#pragma unroll
  for (int j = 0; j < 8; ++j) {
    const int i = base + j;
    if (i < n) {
      const int id = excl + loc[j];
      ids[i] = id;
      const int f = loc[j] - ((j > 0) ? loc[j - 1] : 0);
      if (f) startg[id - 1] = i;
    }
  }
  __syncthreads();
  for (int j = t; j < m; j += 256)
    cntg[j] = (float)((((j + 1) < m) ? startg[j + 1] : n) - startg[j]);
  __syncthreads();
  return m;
}

// ---------------------------------------------------------------------------
// Fused meta (blockIdx.y==7, x==0: 1-block scan) + prep conversions
// (blockIdx.y<7: x->f16, Wi->f16, Wo->hi/lo f16 split).
// ---------------------------------------------------------------------------
__global__ __launch_bounds__(256)
void meta_prep(const float* __restrict__ mw, const float* __restrict__ mb,
               const float* __restrict__ gw, const float* __restrict__ gb,
               int* __restrict__ mi,
               int* __restrict__ start1, float* __restrict__ cnt1,
               int* __restrict__ start2, float* __restrict__ cnt2,
               int* __restrict__ gmap,
               const float* __restrict__ x,
               const float* __restrict__ wi0, const float* __restrict__ wi1,
               const float* __restrict__ wi2,
               const float* __restrict__ wo0, const float* __restrict__ wo1,
               const float* __restrict__ wo2,
               _Float16* __restrict__ xh, _Float16* __restrict__ wiH,
               _Float16* __restrict__ woH, _Float16* __restrict__ woL)
{
  __shared__ int ids1[TT];
  __shared__ int ids2[TT];
  __shared__ int wsum[256];
  __shared__ double dsh[256];
  const int t = threadIdx.x;

  if (blockIdx.y == 7) {
    if (blockIdx.x != 0) return;
    double s1 = 0.0, s2 = 0.0;
    for (int i = t; i < TD; i += 256) { s1 += (double)mw[i]; s2 += (double)gw[i]; }
    dsh[t] = s1; __syncthreads();
    for (int off = 128; off > 0; off >>= 1) {
      if (t < off) dsh[t] += dsh[t + off];
      __syncthreads();
    }
    const double c1 = dsh[0] + (double)mb[0];
    __syncthreads();
    dsh[t] = s2; __syncthreads();
    for (int off = 128; off > 0; off >>= 1) {
      if (t < off) dsh[t] += dsh[t + off];
      __syncthreads();
    }
    const double c2 = dsh[0] + (double)gb[0];
    __syncthreads();

    const int m1 = scan_phase(TT, c1, ids1, start1, cnt1, wsum, t);
    const int m2 = scan_phase(m1, c2, ids2, start2, cnt2, wsum, t);

    int i0 = TT;
    if (m1 >= 1 && m2 >= 1) i0 = start1[start2[0]];
    const int ntok = TT - i0;

    if (t == 0) {
      mi[MI_M1] = m1; mi[MI_M2] = m2; mi[MI_NTOK] = ntok;
      const int offcw = TB * ntok * TD;
      mi[MI_OFF_CW] = offcw;
      mi[MI_OFF_BW] = offcw + TB * TT * TT;
      mi[MI_OFF_GW] = offcw + TB * TT * TT + TB * m1 * m1;
      mi[MI_MCHAR] = TB * TT;
      mi[MI_MBLOCK] = TB * m1;
      mi[MI_MGLOB] = TB * m2;
      mi[MI_SEQC] = TT;
      mi[MI_SEQB] = m1;
      mi[MI_SEQG] = m2;
    }
    for (int i = i0 + t; i < TT; i += 256)
      gmap[i - i0] = ids2[ids1[i] - 1] - 1;
    return;
  }

  // --- prep regions ---
  const int r = blockIdx.y;
  const float* src;
  _Float16* dh;
  _Float16* dl = nullptr;
  int n;
  if (r == 0)      { src = x;   dh = xh;                              n = TB * TT * TD; }
  else if (r == 1) { src = wi0; dh = wiH;                             n = 3 * TD * TD; }
  else if (r == 2) { src = wi1; dh = wiH + (size_t)1 * 3 * TD * TD;   n = 3 * TD * TD; }
  else if (r == 3) { src = wi2; dh = wiH + (size_t)2 * 3 * TD * TD;   n = 3 * TD * TD; }
  else if (r == 4) { src = wo0; dh = woH; dl = woL;                   n = TD * TD; }
  else if (r == 5) { src = wo1; dh = woH + (size_t)TD * TD; dl = woL + (size_t)TD * TD; n = TD * TD; }
  else             { src = wo2; dh = woH + (size_t)2 * TD * TD; dl = woL + (size_t)2 * TD * TD; n = TD * TD; }

  const int stride = gridDim.x * 256 * 4;
  for (int i = (blockIdx.x * 256 + threadIdx.x) * 4; i < n; i += stride) {
    const float4 v = *(const float4*)&src[i];
    const float a[4] = {v.x, v.y, v.z, v.w};
    half4 h, l;
#pragma unroll
    for (int e = 0; e < 4; ++e) {
      const _Float16 hh = (_Float16)a[e];
      h[e] = hh;
      l[e] = (_Float16)(a[e] - (float)hh);
    }
    *(half4*)&dh[i] = h;
    if (dl) *(half4*)&dl[i] = l;
  }
}

// ---------------------------------------------------------------------------
// qkv GEMM 128m x 64n tile, pure-f16 staging, 2-phase pipelined.
// C[M,N] = A[M,512] @ W[N,512]^T + bias.   (byte-exact R13)
// ---------------------------------------------------------------------------
__global__ __launch_bounds__(256)
void gemm_mfma(const _Float16* __restrict__ A, const _Float16* __restrict__ W,
               const float* __restrict__ bias, _Float16* __restrict__ C,
               const int* __restrict__ mi, int m_slot, int N)
{
  const int M = mi[m_slot];
  const int bm = blockIdx.y * 128;
  if (bm >= M) return;
  const int bn = blockIdx.x * 64;
  __shared__ _Float16 Ah[2][128][40];
  __shared__ _Float16 Wh[2][64][40];

  const int t = threadIdx.x;
  const int wv = t >> 6;
  const int lane = t & 63;
  const int l15 = lane & 15;
  const int quad = lane >> 4;
  const int srowA = t >> 1;
  const int ssegA = (t & 1) * 16;
  const int srowW = t >> 2;
  const int ssegW = (t & 3) * 8;
  const int ar = bm + srowA;
  const size_t abase = (size_t)ar * TD + ssegA;
  const size_t wbase = (size_t)(bn + srowW) * TD + ssegW;

  floatx4 acc[2][4];
#pragma unroll
  for (int i = 0; i < 2; ++i)
#pragma unroll
    for (int j = 0; j < 4; ++j) acc[i][j] = (floatx4){0.f, 0.f, 0.f, 0.f};

  const half8 h8z = {};
  half8 pa0, pa1, pw;

  auto LOADT = [&](int kk) {
    pa0 = h8z; pa1 = h8z;
    if (ar < M) {
      pa0 = *(const half8*)&A[abase + kk];
      pa1 = *(const half8*)&A[abase + kk + 8];
    }
    pw = *(const half8*)&W[wbase + kk];
  };
  auto WRITET = [&](int buf) {
    *(half8*)&Ah[buf][srowA][ssegA] = pa0;
    *(half8*)&Ah[buf][srowA][ssegA + 8] = pa1;
    *(half8*)&Wh[buf][srowW][ssegW] = pw;
  };

  LOADT(0);
  for (int it = 0; it < TD / 32; ++it) {
    const int buf = it & 1;
    WRITET(buf);
    if (it + 1 < TD / 32) LOADT((it + 1) * 32);
    barrier_nodrain();
    half8 ah[2];
#pragma unroll
    for (int mp = 0; mp < 2; ++mp)
      ah[mp] = *(const half8*)&Ah[buf][wv * 32 + mp * 16 + l15][quad * 8];
#pragma unroll
    for (int np = 0; np < 4; ++np) {
      const half8 bh = *(const half8*)&Wh[buf][np * 16 + l15][quad * 8];
#pragma unroll
      for (int mp = 0; mp < 2; ++mp)
        acc[mp][np] = mfma16(ah[mp], bh, acc[mp][np]);
    }
  }
  float bv[4];
#pragma unroll
  for (int np = 0; np < 4; ++np) bv[np] = bias[bn + np * 16 + l15];
#pragma unroll
  for (int mp = 0; mp < 2; ++mp) {
#pragma unroll
    for (int r = 0; r < 4; ++r) {
      const int row = bm + wv * 32 + mp * 16 + quad * 4 + r;
      if (row < M) {
        _Float16* cp = &C[(size_t)row * N + bn];
#pragma unroll
        for (int np = 0; np < 4; ++np)
          cp[np * 16 + l15] = (_Float16)(acc[mp][np][r] + bv[np]);
      }
    }
  }
}

// ---------------------------------------------------------------------------
// Proj GEMM with fused combine, 64m x 64n tile, split-f16 (pre-split W),
// 2-phase pipelined.   (byte-exact R13)
// ---------------------------------------------------------------------------
__global__ __launch_bounds__(256)
void gemm_norm_mfma(const _Float16* __restrict__ Ob, const float* __restrict__ lb,
                    const _Float16* __restrict__ Whg, const _Float16* __restrict__ Wlg,
                    const float* __restrict__ bias,
                    float* __restrict__ C, const int* __restrict__ mi,
                    int m_slot, int seq_slot)
{
  const int M = mi[m_slot];
  const int bm = blockIdx.y * 64;
  if (bm >= M) return;
  const int seq = mi[seq_slot];
  const int bn = blockIdx.x * 64;
  __shared__ _Float16 Ah[2][64][40];
  __shared__ _Float16 Al[2][64][40];
  __shared__ _Float16 Wh[2][64][40];
  __shared__ _Float16 Wl[2][64][40];

  const int t = threadIdx.x;
  const int wv = t >> 6;
  const int lane = t & 63;
  const int l15 = lane & 15;
  const int quad = lane >> 4;
  const int srow = t >> 2;
  const int sseg = (t & 3) * 8;

  const int ar = bm + srow;
  const int ab = (ar >= seq) ? 1 : 0;
  const int aq = ar - ab * seq;
  const size_t wbase = (size_t)(bn + srow) * TD + sseg;

  floatx4 acc[4];
#pragma unroll
  for (int j = 0; j < 4; ++j) acc[j] = (floatx4){0.f, 0.f, 0.f, 0.f};

  const half8 h8z = {};
  half8 pOb[KC];
  float plb[KC];
  half8 pwh, pwl;

  auto LOADT = [&](int kk) {
    if (ar < M) {
      const size_t off = (size_t)ar * TD + kk + sseg;
#pragma unroll
      for (int z = 0; z < KC; ++z)
        pOb[z] = *(const half8*)&Ob[(size_t)z * 2097152 + off];
      const int h = kk >> 6;
      const size_t lidx = ((size_t)(ab * TH + h)) * 2048 + aq;
#pragma unroll
      for (int z = 0; z < KC; ++z) plb[z] = lb[(size_t)z * 32768 + lidx];
    } else {
#pragma unroll
      for (int z = 0; z < KC; ++z) { pOb[z] = h8z; plb[z] = 1.f; }
    }
    pwh = *(const half8*)&Whg[wbase + kk];
    pwl = *(const half8*)&Wlg[wbase + kk];
  };
  auto WRITET = [&](int buf) {
    float aa[8] = {0.f, 0.f, 0.f, 0.f, 0.f, 0.f, 0.f, 0.f};
    if (ar < M) {
#pragma unroll
      for (int z = 0; z < KC; ++z)
#pragma unroll
        for (int e = 0; e < 8; ++e) aa[e] += (float)pOb[z][e];
      const float lt = plb[0] + plb[1] + plb[2] + plb[3];
      const float linv = 1.f / lt;
#pragma unroll
      for (int e = 0; e < 8; ++e) aa[e] *= linv;
    }
    half8 hi, lo;
#pragma unroll
    for (int e = 0; e < 8; ++e) {
      const _Float16 h = (_Float16)aa[e];
      hi[e] = h; lo[e] = (_Float16)(aa[e] - (float)h);
    }
    *(half8*)&Ah[buf][srow][sseg] = hi;
    *(half8*)&Al[buf][srow][sseg] = lo;
    *(half8*)&Wh[buf][srow][sseg] = pwh;
    *(half8*)&Wl[buf][srow][sseg] = pwl;
  };

  LOADT(0);
  for (int it = 0; it < TD / 32; ++it) {
    const int buf = it & 1;
    WRITET(buf);
    if (it + 1 < TD / 32) LOADT((it + 1) * 32);
    barrier_nodrain();
    const half8 ah = *(const half8*)&Ah[buf][wv * 16 + l15][quad * 8];
    const half8 al = *(const half8*)&Al[buf][wv * 16 + l15][quad * 8];
#pragma unroll
    for (int np = 0; np < 4; ++np) {
      const half8 bh = *(const half8*)&Wh[buf][np * 16 + l15][quad * 8];
      const half8 bl = *(const half8*)&Wl[buf][np * 16 + l15][quad * 8];
      acc[np] = mfma16(al, bh, acc[np]);
      acc[np] = mfma16(ah, bl, acc[np]);
      acc[np] = mfma16(ah, bh, acc[np]);
    }
  }
  float bv[4];
#pragma unroll
  for (int np = 0; np < 4; ++np) bv[np] = bias[bn + np * 16 + l15];
#pragma unroll
  for (int r = 0; r < 4; ++r) {
    const int row = bm + wv * 16 + quad * 4 + r;
    if (row < M) {
      float* cp = &C[(size_t)row * 512 + bn];
#pragma unroll
      for (int np = 0; np < 4; ++np)
        cp[np * 16 + l15] = acc[np][r] + bv[np];
    }
  }
}

// ---------------------------------------------------------------------------
// attn pass1, split-K x4 (z = chunk), S^T-trick, 2-phase pipelined K/V LDS.
// q-tile 128, 4 waves x 32 q.   (byte-exact R13)
// ---------------------------------------------------------------------------
__global__ __launch_bounds__(256)
void attn1_mfma(const _Float16* __restrict__ qkv,
                float* __restrict__ lbase, _Float16* __restrict__ Obase,
                const int* __restrict__ mi, int seq_slot)
{
  const int seq = mi[seq_slot];
  const int q0 = blockIdx.x * 128;
  if (q0 >= seq) return;
  const int b = blockIdx.y >> 3, h = blockIdx.y & 7;
  const int z = blockIdx.z;
  float* lP = lbase + (size_t)z * 32768;
  _Float16* oP = Obase + (size_t)z * 2097152;
  const int t = threadIdx.x;
  const int wv = t >> 6;
  const int lane = t & 63;
  const int l15 = lane & 15;
  const int quad = lane >> 4;

  __shared__ __align__(16) char smem_raw[36864];   // 2 x (Kf 9216 + Vt 9216)
  float (*Ot)[68] = (float (*)[68])smem_raw;       // epilogue reuse (buf 0)

  half8 qB[2][2];
#pragma unroll
  for (int mp = 0; mp < 2; ++mp) {
    const int qrow = q0 + wv * 32 + mp * 16 + l15;
#pragma unroll
    for (int c = 0; c < 2; ++c) {
      half8 v = {};
      if (qrow < seq)
        v = *(const half8*)&qkv[((size_t)(b * seq + qrow)) * 1536 + h * 64 + c * 32 + quad * 8];
      qB[mp][c] = v;
    }
  }
  half4 onesA;
#pragma unroll
  for (int j = 0; j < 4; ++j) onesA[j] = (_Float16)1.0f;

  floatx4 oacc[2][4];
#pragma unroll
  for (int i = 0; i < 2; ++i)
#pragma unroll
    for (int j = 0; j < 4; ++j) oacc[i][j] = (floatx4){0.f, 0.f, 0.f, 0.f};
  floatx4 lacc[2] = {(floatx4){0.f, 0.f, 0.f, 0.f}, (floatx4){0.f, 0.f, 0.f, 0.f}};

  const int nkt = (seq + 63) >> 6;
  const int nkc = (nkt + KC - 1) / KC;
  const int kt_beg = z * nkc;
  const int kt_end = min(kt_beg + nkc, nkt);

  // staging geometry
  const int krow = t >> 2;
  const int kseg = (t & 3) * 16;
  const int tp = lane & 31;
  const int dsel = lane >> 5;
  const int dbase = wv * 16 + dsel * 8;

  const half8 h8z = {};
  half8 pk0, pk1, pva, pvb;

  auto LOADKV = [&](int kt) {
    const int k0 = kt * 64;
    pk0 = h8z; pk1 = h8z; pva = h8z; pvb = h8z;
    const int kg = k0 + krow;
    if (kg < seq) {
      const _Float16* base = &qkv[((size_t)(b * seq + kg)) * 1536 + 512 + h * 64 + kseg];
      pk0 = *(const half8*)base;
      pk1 = *(const half8*)(base + 8);
    }
    const int kg0 = k0 + tp * 2;
    if (kg0 < seq)
      pva = *(const half8*)&qkv[((size_t)(b * seq + kg0)) * 1536 + 1024 + h * 64 + dbase];
    if (kg0 + 1 < seq)
      pvb = *(const half8*)&qkv[((size_t)(b * seq + kg0 + 1)) * 1536 + 1024 + h * 64 + dbase];
  };

  LOADKV(kt_beg);
  for (int kt = kt_beg; kt < kt_end; ++kt) {
    char* sb = smem_raw + (size_t)((kt - kt_beg) & 1) * 18432;
    _Float16 (*Kf)[72] = (_Float16 (*)[72])sb;
    _Float16 (*Vt)[72] = (_Float16 (*)[72])(sb + 9216);

    *(half8*)&Kf[krow][kseg] = pk0;
    *(half8*)&Kf[krow][kseg + 8] = pk1;
#pragma unroll
    for (int j = 0; j < 8; ++j) {
      half2_t pkk; pkk[0] = pva[j]; pkk[1] = pvb[j];
      *(half2_t*)&Vt[dbase + j][tp * 2] = pkk;
    }
    if (kt + 1 < kt_end) LOADKV(kt + 1);
    barrier_nodrain();

    const int k0 = kt * 64;
    const bool kfull = (k0 + 64 <= seq);
#pragma unroll
    for (int p = 0; p < 4; ++p) {
      floatx4 sT[2] = {(floatx4){0.f, 0.f, 0.f, 0.f}, (floatx4){0.f, 0.f, 0.f, 0.f}};
#pragma unroll
      for (int c = 0; c < 2; ++c) {
        const half8 kA = *(const half8*)&Kf[p * 16 + l15][c * 32 + quad * 8];
#pragma unroll
        for (int mp = 0; mp < 2; ++mp)
          sT[mp] = mfma16(kA, qB[mp][c], sT[mp]);
      }
      half4 vA[4];
#pragma unroll
      for (int dblk = 0; dblk < 4; ++dblk)
        vA[dblk] = *(const half4*)&Vt[dblk * 16 + l15][p * 16 + quad * 4];
      const int kg = k0 + p * 16 + quad * 4;
#pragma unroll
      for (int mp = 0; mp < 2; ++mp) {
        half4 eB;
        if (kfull) {
#pragma unroll
          for (int r = 0; r < 4; ++r)
            eB[r] = (_Float16)__expf(sT[mp][r] * 0.125f);
        } else {
#pragma unroll
          for (int r = 0; r < 4; ++r) {
            const float e = (kg + r < seq) ? __expf(sT[mp][r] * 0.125f) : 0.f;
            eB[r] = (_Float16)e;
          }
        }
        lacc[mp] = mfma16k16(onesA, eB, lacc[mp]);
#pragma unroll
        for (int dblk = 0; dblk < 4; ++dblk)
          oacc[mp][dblk] = mfma16k16(vA[dblk], eB, oacc[mp][dblk]);
      }
    }
  }

  __syncthreads();   // K/V LDS done — reuse as Ot

#pragma unroll
  for (int mp = 0; mp < 2; ++mp) {
#pragma unroll
    for (int dblk = 0; dblk < 4; ++dblk)
      *(floatx4*)&Ot[wv * 16 + l15][dblk * 16 + quad * 4] = oacc[mp][dblk];
    const int ql = lane >> 2;
    const int dseg = (lane & 3) * 4;
    const int qg = q0 + wv * 32 + mp * 16 + ql;
    if (qg < seq) {
      _Float16* op = &oP[((size_t)(b * seq + qg)) * 512 + h * 64];
#pragma unroll
      for (int u = 0; u < 4; ++u) {
        const float4 v = *(const float4*)&Ot[wv * 16 + ql][u * 16 + dseg];
        half4 hv;
        hv[0] = (_Float16)v.x; hv[1] = (_Float16)v.y;
        hv[2] = (_Float16)v.z; hv[3] = (_Float16)v.w;
        *(half4*)(op + u * 16 + dseg) = hv;
      }
    }
    if (quad == 0) {
      const int qg2 = q0 + wv * 32 + mp * 16 + l15;
      if (qg2 < seq)
        lP[((size_t)(b * TH + h)) * 2048 + qg2] = lacc[mp][0];
    }
  }
}

// ---------------------------------------------------------------------------
// attn pass2 (plain f16 MFMA), q-tile 64 x k-tile 128; Linv = 1/(sum_z l_z).
// Q per-lane in regs (prefetch h+1), K double-buffered LDS, Linv precomputed.
// (byte-exact R13)
// ---------------------------------------------------------------------------
__global__ __launch_bounds__(256)
void attn2_mfma(const _Float16* __restrict__ qkv,
                const float* __restrict__ lb,
                float* __restrict__ outb, const int* __restrict__ mi,
                int seq_slot, int off_slot)
{
  const int seq = mi[seq_slot];
  const int q0 = blockIdx.y * 64;
  const int k0 = blockIdx.x * 128;
  if (q0 >= seq || k0 >= seq) return;
  const int b = blockIdx.z;
  const int woff = mi[off_slot];
  float* wout = outb + (size_t)woff + (size_t)b * seq * seq;

  __shared__ _Float16 Ksh[2][128][72];
  __shared__ float Linv8[TH][64];

  const int t = threadIdx.x;
  const int wv = t >> 6;
  const int lane = t & 63;
  const int l15 = lane & 15;
  const int quad = lane >> 4;
  const int srowK = t >> 1;
  const int ssegK = (t & 1) * 32;

  // all-heads Linv, once
  for (int i = t; i < TH * 64; i += 256) {
    const int hh = i >> 6;
    const int qq = i & 63;
    float lv = 1.f;
    if (q0 + qq < seq) {
      const size_t lidx = ((size_t)(b * TH + hh)) * 2048 + q0 + qq;
      float lt = 0.f;
#pragma unroll
      for (int zz = 0; zz < KC; ++zz) lt += lb[(size_t)zz * 32768 + lidx];
      lv = lt;
    }
    Linv8[hh][qq] = 1.f / lv;
  }

  floatx4 acc[8];
#pragma unroll
  for (int j = 0; j < 8; ++j) acc[j] = (floatx4){0.f, 0.f, 0.f, 0.f};

  const int qr = q0 + wv * 16 + l15;
  const int kr = k0 + srowK;
  const bool qok = (qr < seq);
  const bool kok = (kr < seq);
  const size_t qoff = (size_t)(b * seq + qr) * 1536 + quad * 8;
  const size_t koff = (size_t)(b * seq + kr) * 1536 + 512 + ssegK;

  const half8 h8z = {};
  half8 pk[4];
  half8 qcur0, qcur1, qnxt0, qnxt1;

  auto LOADK = [&](int h) {
#pragma unroll
    for (int u = 0; u < 4; ++u) {
      pk[u] = h8z;
      if (kok) pk[u] = *(const half8*)&qkv[koff + h * 64 + u * 8];
    }
  };
  auto LOADQ = [&](int h, half8& d0, half8& d1) {
    d0 = h8z; d1 = h8z;
    if (qok) {
      d0 = *(const half8*)&qkv[qoff + h * 64];
      d1 = *(const half8*)&qkv[qoff + h * 64 + 32];
    }
  };

  LOADK(0);
  LOADQ(0, qcur0, qcur1);
  for (int h = 0; h < TH; ++h) {
    const int buf = h & 1;
#pragma unroll
    for (int u = 0; u < 4; ++u)
      *(half8*)&Ksh[buf][srowK][ssegK + u * 8] = pk[u];
    if (h + 1 < TH) { LOADK(h + 1); LOADQ(h + 1, qnxt0, qnxt1); }
    barrier_nodrain();

    float lv[4];
#pragma unroll
    for (int r = 0; r < 4; ++r)
      lv[r] = Linv8[h][wv * 16 + quad * 4 + r];

#pragma unroll
    for (int np = 0; np < 8; ++np) {
      const half8 bf0 = *(const half8*)&Ksh[buf][np * 16 + l15][quad * 8];
      const half8 bf1 = *(const half8*)&Ksh[buf][np * 16 + l15][32 + quad * 8];
      floatx4 s = (floatx4){0.f, 0.f, 0.f, 0.f};
      s = mfma16(qcur0, bf0, s);
      s = mfma16(qcur1, bf1, s);
#pragma unroll
      for (int r = 0; r < 4; ++r)
        acc[np][r] += __expf(s[r] * 0.125f) * lv[r];
    }
    qcur0 = qnxt0; qcur1 = qnxt1;
  }

#pragma unroll
  for (int r = 0; r < 4; ++r) {
    const int qg = q0 + wv * 16 + quad * 4 + r;
    if (qg >= seq) continue;
    float* rowp = wout + (size_t)qg * seq;
#pragma unroll
    for (int np = 0; np < 8; ++np) {
      const int col = k0 + np * 16 + l15;
      if (col < seq) rowp[col] = acc[np][r] * 0.125f;
    }
  }
}

// ---------------------------------------------------------------------------
// merge: averages rows of src (f32) into f16 output (same rounding as the
// old GEMM staging applied, so downstream is bitwise identical).
// ---------------------------------------------------------------------------
__global__ __launch_bounds__(256)
void merge_kernel(const float* __restrict__ src, _Float16* __restrict__ dst,
                  const int* __restrict__ start, const float* __restrict__ cnt,
                  const int* __restrict__ mi, int seqin_slot, int seqout_slot)
{
  const int j = blockIdx.x;
  const int b = blockIdx.y;
  const int seqo = mi[seqout_slot];
  if (j >= seqo) return;
  const int seqi = mi[seqin_slot];
  const int s = start[j];
  const float cf = cnt[j];
  const int n = (int)cf;
  const int d0 = threadIdx.x * 2;
  float s0 = 0.f, s1 = 0.f;
  const float* p = &src[((size_t)b * seqi + s) * TD + d0];
  for (int i = 0; i < n; ++i) {
    const float2 v = *(const float2*)p;
    s0 += v.x; s1 += v.y;
    p += TD;
  }
  const float inv = 1.f / (cf + 1e-10f);
  half2_t o;
  o[0] = (_Float16)(s0 * inv);
  o[1] = (_Float16)(s1 * inv);
  *(half2_t*)&dst[((size_t)b * seqo + j) * TD + d0] = o;
}

__global__ __launch_bounds__(256)
void expand_kernel(const float* __restrict__ gout, float* __restrict__ dout,
                   const int* __restrict__ gmap, const int* __restrict__ mi)
{
  const int j = blockIdx.x;
  const int b = blockIdx.y;
  const int ntok = mi[MI_NTOK];
  if (j >= ntok) return;
  const int m2 = mi[MI_M2];
  const int g = gmap[j];
  const int d0 = threadIdx.x * 2;
  const float2 v = *(const float2*)&gout[((size_t)b * m2 + g) * TD + d0];
  *(float2*)&dout[((size_t)b * ntok + j) * TD + d0] = v;
}

// ---------------------------------------------------------------------------
extern "C" void kernel_launch(void* const* d_in, const int* in_sizes, int n_in,
                              void* d_out, int out_size, void* d_ws, size_t ws_size,
                              hipStream_t stream)
{
  const float* x   = (const float*)d_in[0];
  const float* cWi = (const float*)d_in[1];
  const float* cbi = (const float*)d_in[2];
  const float* cWo = (const float*)d_in[3];
  const float* cbo = (const float*)d_in[4];
  const float* bWi = (const float*)d_in[5];
  const float* bbi = (const float*)d_in[6];
  const float* bWo = (const float*)d_in[7];
  const float* bbo = (const float*)d_in[8];
  const float* gWi = (const float*)d_in[9];
  const float* gbi = (const float*)d_in[10];
  const float* gWo = (const float*)d_in[11];
  const float* gbo = (const float*)d_in[12];
  const float* mw  = (const float*)d_in[13];
  const float* mbv = (const float*)d_in[14];
  const float* gw  = (const float*)d_in[15];
  const float* gbv = (const float*)d_in[16];
  float* outf = (float*)d_out;

  char* wsb = (char*)d_ws;
  int*   mi     = (int*)(wsb);
  int*   start1 = (int*)(wsb + 1024);
  float* cnt1   = (float*)(wsb + 1024 + 8192);
  int*   start2 = (int*)(wsb + 1024 + 2 * 8192);
  float* cnt2   = (float*)(wsb + 1024 + 3 * 8192);
  int*   gmap   = (int*)(wsb + 1024 + 4 * 8192);
  float* lbase  = (float*)(wsb + 65536);                    // KC x 32768 f32 (512 KB)
  _Float16* qkv = (_Float16*)(wsb + 655360);                // 4096x1536 f16 (12.6 MB)
  _Float16* Obase = (_Float16*)(wsb + 655360 + 12582912);   // KC x 4 MB f16
  float* stg_o  = (float*)(wsb + 30015488);                 // 8 MB f32
  _Float16* stg_mh = (_Float16*)(wsb + 38404096);           // 4 MB f16
  _Float16* xh  = (_Float16*)(wsb + 42598400);              // 4 MB f16
  _Float16* wiH = (_Float16*)(wsb + 46792704);              // 3 x 1536x512 f16 (4.7 MB)
  _Float16* woH = (_Float16*)(wsb + 51511296);              // 3 x 512x512 f16 (1.6 MB)
  _Float16* woL = (_Float16*)(wsb + 53084160);              // 3 x 512x512 f16 (1.6 MB)

  const dim3 blk(256);

  meta_prep<<<dim3(256, 8), blk, 0, stream>>>(mw, mbv, gw, gbv, mi, start1, cnt1,
                                              start2, cnt2, gmap,
                                              x, cWi, bWi, gWi, cWo, bWo, gWo,
                                              xh, wiH, woH, woL);

  // ---- char stage ----
  gemm_mfma<<<dim3(24, 32), blk, 0, stream>>>(xh, wiH, cbi, qkv, mi, MI_MCHAR, 1536);
  attn1_mfma<<<dim3(16, 16, KC), blk, 0, stream>>>(qkv, lbase, Obase, mi, MI_SEQC);
  attn2_mfma<<<dim3(16, 32, 2), blk, 0, stream>>>(qkv, lbase, outf, mi, MI_SEQC, MI_OFF_CW);
  gemm_norm_mfma<<<dim3(8, 64), blk, 0, stream>>>(Obase, lbase, woH, woL, cbo, stg_o, mi, MI_MCHAR, MI_SEQC);
  merge_kernel<<<dim3(2048, 2), blk, 0, stream>>>(stg_o, stg_mh, start1, cnt1, mi, MI_SEQC, MI_SEQB);

  // ---- block stage ----
  gemm_mfma<<<dim3(24, 32), blk, 0, stream>>>(stg_mh, wiH + (size_t)786432, bbi, qkv, mi, MI_MBLOCK, 1536);
  attn1_mfma<<<dim3(16, 16, KC), blk, 0, stream>>>(qkv, lbase, Obase, mi, MI_SEQB);
  attn2_mfma<<<dim3(16, 32, 2), blk, 0, stream>>>(qkv, lbase, outf, mi, MI_SEQB, MI_OFF_BW);
  gemm_norm_mfma<<<dim3(8, 64), blk, 0, stream>>>(Obase, lbase, woH + (size_t)262144, woL + (size_t)262144, bbo, stg_o, mi, MI_MBLOCK, MI_SEQB);
  merge_kernel<<<dim3(2048, 2), blk, 0, stream>>>(stg_o, stg_mh, start2, cnt2, mi, MI_SEQB, MI_SEQG);

  // ---- glob stage ----
  gemm_mfma<<<dim3(24, 32), blk, 0, stream>>>(stg_mh, wiH + (size_t)2 * 786432, gbi, qkv, mi, MI_MGLOB, 1536);
  attn1_mfma<<<dim3(16, 16, KC), blk, 0, stream>>>(qkv, lbase, Obase, mi, MI_SEQG);
  attn2_mfma<<<dim3(16, 32, 2), blk, 0, stream>>>(qkv, lbase, outf, mi, MI_SEQG, MI_OFF_GW);
  gemm_norm_mfma<<<dim3(8, 64), blk, 0, stream>>>(Obase, lbase, woH + (size_t)2 * 262144, woL + (size_t)2 * 262144, gbo, stg_o, mi, MI_MGLOB, MI_SEQG);
  expand_kernel<<<dim3(2048, 2), blk, 0, stream>>>(stg_o, outf, gmap, mi);

  (void)in_sizes; (void)n_in; (void)out_size; (void)ws_size;
}